// Round 1
// baseline (93.887 us; speedup 1.0000x reference)
//
#include <hip/hip_runtime.h>

#define B_TOTAL 8192
#define IN_DIM  64
#define OUT_DIM 64
#define NSPL    8
#define NBRK    20
#define NINT    19

#define BTILE   16   // rows of x per block
#define RPT     4    // rows per thread (4 b-groups * 4 = 16)

// Param table: [IN_DIM][OUT_DIM][8] floats = {k3, b4, k2, c1, c5, c6, c7, c8}
//   k3 = b3*log2(e), k2 = b2*ln2, c1 = b1*G*ln2, c5..c8 = b5..b8*G, G = softplus(raw_gamma)/OUT
__device__ float g_table[IN_DIM * OUT_DIM * 8];

__global__ __launch_bounds__(256) void precompute_params(
    const float* __restrict__ raw_gamma, const float* __restrict__ w,
    const float* __restrict__ breaks, const float* __restrict__ coefs,
    const float* __restrict__ mu_p, const float* __restrict__ sigma_p)
{
    int gid = blockIdx.x * 256 + threadIdx.x;   // gid = o*IN_DIM + i (w layout row-major)
    if (gid >= OUT_DIM * IN_DIM) return;
    int o = gid >> 6;
    int i = gid & 63;

    float mu = mu_p[0], sigma = sigma_p[0];
    float wc = fminf(fmaxf(w[gid], -5.5f), 37.9f);
    float wn = (wc - mu) / sigma;

    float bs[NSPL];
    #pragma unroll
    for (int s = 0; s < NSPL; ++s) {
        const float* br = breaks + s * NBRK;
        float lo = br[0];
        float hi = br[NBRK - 1] - 1e-6f;
        float wl = fminf(fmaxf(wn, lo), hi);
        // searchsorted(br, wl, 'left') == count of br[k] < wl
        int cnt = 0;
        #pragma unroll
        for (int k = 0; k < NBRK; ++k) cnt += (br[k] < wl) ? 1 : 0;
        int idx = cnt - 1;
        idx = idx < 0 ? 0 : (idx > NINT - 1 ? NINT - 1 : idx);
        const float* a = coefs + (s * NINT + idx) * 4;
        float t = wl - br[idx];
        bs[s] = ((a[0] * t + a[1]) * t + a[2]) * t + a[3];
    }

    float g = raw_gamma[gid];
    float sp = fmaxf(g, 0.0f) + log1pf(expf(-fabsf(g)));   // stable softplus
    float G = sp * (1.0f / (float)OUT_DIM);

    const float LOG2E = 1.4426950408889634f;
    const float LN2   = 0.6931471805599453f;

    float* t8 = g_table + (i * OUT_DIM + o) * 8;
    t8[0] = bs[2] * LOG2E;     // k3
    t8[1] = bs[3];             // b4
    t8[2] = bs[1] * LN2;       // k2
    t8[3] = bs[0] * G * LN2;   // c1
    t8[4] = bs[4] * G;         // c5
    t8[5] = bs[5] * G;         // c6
    t8[6] = bs[6] * G;         // c7
    t8[7] = bs[7] * G;         // c8
}

__global__ __launch_bounds__(256) void log_act_kernel(
    const float* __restrict__ x, float* __restrict__ out)
{
    __shared__ float xs[BTILE][IN_DIM];
    const int tid = threadIdx.x;
    const int b0  = blockIdx.x * BTILE;

    // Stage x tile with ReLU: 256 threads * float4 = 1024 floats = 16 rows
    {
        const float4* xg = (const float4*)(x + b0 * IN_DIM);
        float4 v = xg[tid];
        float* dst = &xs[0][0] + tid * 4;
        dst[0] = fmaxf(v.x, 0.0f);
        dst[1] = fmaxf(v.y, 0.0f);
        dst[2] = fmaxf(v.z, 0.0f);
        dst[3] = fmaxf(v.w, 0.0f);
    }
    __syncthreads();

    const int o  = tid & 63;
    const int bg = tid >> 6;   // 0..3

    float acc[RPT];
    #pragma unroll
    for (int r = 0; r < RPT; ++r) acc[r] = 0.0f;

    for (int i = 0; i < IN_DIM; ++i) {
        const float4* p = (const float4*)(g_table + (i * OUT_DIM + o) * 8);
        float4 p0 = p[0];   // k3, b4, k2, c1
        float4 p1 = p[1];   // c5, c6, c7, c8
        #pragma unroll
        for (int r = 0; r < RPT; ++r) {
            float xv = xs[bg * RPT + r][i];
            // e = 2^(k3*x) = exp(b3*x)
            float e  = __builtin_amdgcn_exp2f(p0.x * xv);
            // base = e-1 ; p = base^b4 = 2^(b4*log2(base)); base=0 -> log2=-inf -> p=0 (correct)
            float lb = __builtin_amdgcn_logf(e - 1.0f);
            float pw = __builtin_amdgcn_exp2f(p0.y * lb);
            // t1 = log2(1+p); t2 = log2(1 + b2*ln2*t1); contribution c1*t2 with ln2 folded into c1
            float t1 = __builtin_amdgcn_logf(1.0f + pw);
            float t2 = __builtin_amdgcn_logf(fmaf(p0.z, t1, 1.0f));
            // poly: c5*x + c6*x^2 + c7*x^3 + c8*x^4 (Horner)
            float q = fmaf(p1.w, xv, p1.z);
            q = fmaf(q, xv, p1.y);
            q = fmaf(q, xv, p1.x);
            acc[r] = fmaf(q, xv, acc[r]);
            acc[r] = fmaf(p0.w, t2, acc[r]);
        }
    }

    #pragma unroll
    for (int r = 0; r < RPT; ++r) {
        int b = b0 + bg * RPT + r;
        out[b * OUT_DIM + o] = acc[r];
    }
}

extern "C" void kernel_launch(void* const* d_in, const int* in_sizes, int n_in,
                              void* d_out, int out_size, void* d_ws, size_t ws_size,
                              hipStream_t stream) {
    const float* x         = (const float*)d_in[0];
    const float* raw_gamma = (const float*)d_in[1];
    const float* w         = (const float*)d_in[2];
    const float* breaks    = (const float*)d_in[3];
    const float* coefs     = (const float*)d_in[4];
    const float* mu_p      = (const float*)d_in[5];
    const float* sigma_p   = (const float*)d_in[6];
    float* out = (float*)d_out;

    precompute_params<<<(OUT_DIM * IN_DIM + 255) / 256, 256, 0, stream>>>(
        raw_gamma, w, breaks, coefs, mu_p, sigma_p);

    log_act_kernel<<<B_TOTAL / BTILE, 256, 0, stream>>>(x, out);
}

// Round 2
// 90.535 us; speedup vs baseline: 1.0370x; 1.0370x over previous
//
#include <hip/hip_runtime.h>

#define B_TOTAL 8192
#define IN_DIM  64
#define OUT_DIM 64
#define NSPL    8
#define NBRK    20
#define NINT    19

#define BTILE   16   // rows of x per block
#define RPT     4    // rows per thread (4 b-groups * 4 = 16)

// Param table: [IN_DIM][OUT_DIM][8] floats = {k3, b4, k2, c1, c5, c6, c7, c8}
//   k3 = b3*log2(e), k2 = b2*ln2, c1 = b1*G*ln2, c5..c8 = b5..b8*G, G = softplus(raw_gamma)/OUT
__device__ float g_table[IN_DIM * OUT_DIM * 8];

__global__ __launch_bounds__(256) void precompute_params(
    const float* __restrict__ raw_gamma, const float* __restrict__ w,
    const float* __restrict__ breaks, const float* __restrict__ coefs,
    const float* __restrict__ mu_p, const float* __restrict__ sigma_p)
{
    int gid = blockIdx.x * 256 + threadIdx.x;   // gid = o*IN_DIM + i (w layout row-major)
    if (gid >= OUT_DIM * IN_DIM) return;
    int o = gid >> 6;
    int i = gid & 63;

    float mu = mu_p[0], sigma = sigma_p[0];
    float wc = fminf(fmaxf(w[gid], -5.5f), 37.9f);
    float wn = (wc - mu) / sigma;

    float bs[NSPL];
    #pragma unroll
    for (int s = 0; s < NSPL; ++s) {
        const float* br = breaks + s * NBRK;
        float lo = br[0];
        float hi = br[NBRK - 1] - 1e-6f;
        float wl = fminf(fmaxf(wn, lo), hi);
        // searchsorted(br, wl, 'left') == count of br[k] < wl
        int cnt = 0;
        #pragma unroll
        for (int k = 0; k < NBRK; ++k) cnt += (br[k] < wl) ? 1 : 0;
        int idx = cnt - 1;
        idx = idx < 0 ? 0 : (idx > NINT - 1 ? NINT - 1 : idx);
        const float* a = coefs + (s * NINT + idx) * 4;
        float t = wl - br[idx];
        bs[s] = ((a[0] * t + a[1]) * t + a[2]) * t + a[3];
    }

    float g = raw_gamma[gid];
    float sp = fmaxf(g, 0.0f) + log1pf(expf(-fabsf(g)));   // stable softplus
    float G = sp * (1.0f / (float)OUT_DIM);

    const float LOG2E = 1.4426950408889634f;
    const float LN2   = 0.6931471805599453f;

    float* t8 = g_table + (i * OUT_DIM + o) * 8;
    t8[0] = bs[2] * LOG2E;     // k3
    t8[1] = bs[3];             // b4
    t8[2] = bs[1] * LN2;       // k2
    t8[3] = bs[0] * G * LN2;   // c1
    t8[4] = bs[4] * G;         // c5
    t8[5] = bs[5] * G;         // c6
    t8[6] = bs[6] * G;         // c7
    t8[7] = bs[7] * G;         // c8
}

__global__ __launch_bounds__(256) void log_act_kernel(
    const float* __restrict__ x, float* __restrict__ out)
{
    __shared__ float xs[BTILE][IN_DIM];
    const int tid = threadIdx.x;
    const int b0  = blockIdx.x * BTILE;

    // Stage x tile with ReLU: 256 threads * float4 = 1024 floats = 16 rows
    {
        const float4* xg = (const float4*)(x + b0 * IN_DIM);
        float4 v = xg[tid];
        float* dst = &xs[0][0] + tid * 4;
        dst[0] = fmaxf(v.x, 0.0f);
        dst[1] = fmaxf(v.y, 0.0f);
        dst[2] = fmaxf(v.z, 0.0f);
        dst[3] = fmaxf(v.w, 0.0f);
    }
    __syncthreads();

    const int o  = tid & 63;
    const int bg = tid >> 6;   // 0..3

    float acc[RPT];
    #pragma unroll
    for (int r = 0; r < RPT; ++r) acc[r] = 0.0f;

    for (int i = 0; i < IN_DIM; ++i) {
        const float4* p = (const float4*)(g_table + (i * OUT_DIM + o) * 8);
        float4 p0 = p[0];   // k3, b4, k2, c1
        float4 p1 = p[1];   // c5, c6, c7, c8

        // xv is WAVE-UNIFORM (all 64 lanes of a wave share bg,r,i; lanes vary
        // only in o). relu(x)==0 for ~50% of entries, and the contribution is
        // then exactly 0 (0^b4=0 -> log1p chain = 0, poly(0)=0). The per-row
        // branch is wave-uniform -> s_cbranch_execz skips 5 transcendentals.
        float xv[RPT];
        #pragma unroll
        for (int r = 0; r < RPT; ++r) xv[r] = xs[bg * RPT + r][i];

        #pragma unroll
        for (int r = 0; r < RPT; ++r) {
            if (xv[r] > 0.0f) {
                float xr = xv[r];
                // e = 2^(k3*x) = exp(b3*x)
                float e  = __builtin_amdgcn_exp2f(p0.x * xr);
                // pw = (e-1)^b4 = 2^(b4*log2(e-1))
                float lb = __builtin_amdgcn_logf(e - 1.0f);
                float pw = __builtin_amdgcn_exp2f(p0.y * lb);
                // t1 = log2(1+pw); t2 = log2(1 + k2*t1); contribution c1*t2 (ln2 folded)
                float t1 = __builtin_amdgcn_logf(1.0f + pw);
                float t2 = __builtin_amdgcn_logf(fmaf(p0.z, t1, 1.0f));
                // poly: c5*x + c6*x^2 + c7*x^3 + c8*x^4 (Horner)
                float q = fmaf(p1.w, xr, p1.z);
                q = fmaf(q, xr, p1.y);
                q = fmaf(q, xr, p1.x);
                acc[r] = fmaf(q, xr, acc[r]);
                acc[r] = fmaf(p0.w, t2, acc[r]);
            }
        }
    }

    #pragma unroll
    for (int r = 0; r < RPT; ++r) {
        int b = b0 + bg * RPT + r;
        out[b * OUT_DIM + o] = acc[r];
    }
}

extern "C" void kernel_launch(void* const* d_in, const int* in_sizes, int n_in,
                              void* d_out, int out_size, void* d_ws, size_t ws_size,
                              hipStream_t stream) {
    const float* x         = (const float*)d_in[0];
    const float* raw_gamma = (const float*)d_in[1];
    const float* w         = (const float*)d_in[2];
    const float* breaks    = (const float*)d_in[3];
    const float* coefs     = (const float*)d_in[4];
    const float* mu_p      = (const float*)d_in[5];
    const float* sigma_p   = (const float*)d_in[6];
    float* out = (float*)d_out;

    precompute_params<<<(OUT_DIM * IN_DIM + 255) / 256, 256, 0, stream>>>(
        raw_gamma, w, breaks, coefs, mu_p, sigma_p);

    log_act_kernel<<<B_TOTAL / BTILE, 256, 0, stream>>>(x, out);
}

// Round 3
// 90.167 us; speedup vs baseline: 1.0413x; 1.0041x over previous
//
#include <hip/hip_runtime.h>

#define B_TOTAL 8192
#define IN_DIM  64
#define OUT_DIM 64
#define NSPL    8
#define NBRK    20
#define NINT    19

#define BTILE   16   // rows of x per block
#define RPT     4    // rows per thread-group (4 waves * 4 = 16)

// Param table: [IN_DIM][OUT_DIM][8] floats = {k3, b4, k2, c1, c5, c6, c7, c8}
//   k3 = b3*log2(e), k2 = b2*ln2, c1 = b1*G*ln2, c5..c8 = b5..b8*G, G = softplus(raw_gamma)/OUT
__device__ float g_table[IN_DIM * OUT_DIM * 8];

// 64 blocks x 64 threads: spread the (cold-HBM-latency-bound) spline eval over 64 CUs
__global__ __launch_bounds__(64) void precompute_params(
    const float* __restrict__ raw_gamma, const float* __restrict__ w,
    const float* __restrict__ breaks, const float* __restrict__ coefs,
    const float* __restrict__ mu_p, const float* __restrict__ sigma_p)
{
    int gid = blockIdx.x * 64 + threadIdx.x;   // gid = o*IN_DIM + i (w layout row-major)
    if (gid >= OUT_DIM * IN_DIM) return;
    int o = gid >> 6;
    int i = gid & 63;

    float mu = mu_p[0], sigma = sigma_p[0];
    float wc = fminf(fmaxf(w[gid], -5.5f), 37.9f);
    float wn = (wc - mu) / sigma;

    float bs[NSPL];
    #pragma unroll
    for (int s = 0; s < NSPL; ++s) {
        const float* br = breaks + s * NBRK;
        float lo = br[0];
        float hi = br[NBRK - 1] - 1e-6f;
        float wl = fminf(fmaxf(wn, lo), hi);
        // searchsorted(br, wl, 'left') == count of br[k] < wl
        int cnt = 0;
        #pragma unroll
        for (int k = 0; k < NBRK; ++k) cnt += (br[k] < wl) ? 1 : 0;
        int idx = cnt - 1;
        idx = idx < 0 ? 0 : (idx > NINT - 1 ? NINT - 1 : idx);
        const float* a = coefs + (s * NINT + idx) * 4;
        float t = wl - br[idx];
        bs[s] = ((a[0] * t + a[1]) * t + a[2]) * t + a[3];
    }

    float g = raw_gamma[gid];
    float sp = fmaxf(g, 0.0f) + log1pf(expf(-fabsf(g)));   // stable softplus
    float G = sp * (1.0f / (float)OUT_DIM);

    const float LOG2E = 1.4426950408889634f;
    const float LN2   = 0.6931471805599453f;

    float* t8 = g_table + (i * OUT_DIM + o) * 8;
    t8[0] = bs[2] * LOG2E;     // k3
    t8[1] = bs[3];             // b4
    t8[2] = bs[1] * LN2;       // k2
    t8[3] = bs[0] * G * LN2;   // c1
    t8[4] = bs[4] * G;         // c5
    t8[5] = bs[5] * G;         // c6
    t8[6] = bs[6] * G;         // c7
    t8[7] = bs[7] * G;         // c8
}

// One row's contribution. xr is WAVE-UNIFORM (lanes differ only in o) ->
// the x>0 branch compiles to exec-mask + s_cbranch_execz, skipping all
// 5 transcendentals + poly for the ~50% of relu(x) entries that are 0
// (exact: 0^b4=0 -> both log1p terms 0, poly(0)=0).
__device__ __forceinline__ void row_contrib(float xr, const float4& p0,
                                            const float4& p1, float& acc)
{
    if (xr > 0.0f) {
        // e = 2^(k3*x) = exp(b3*x)
        float e  = __builtin_amdgcn_exp2f(p0.x * xr);
        // pw = (e-1)^b4 = 2^(b4*log2(e-1))
        float lb = __builtin_amdgcn_logf(e - 1.0f);
        float pw = __builtin_amdgcn_exp2f(p0.y * lb);
        // t1 = log2(1+pw); t2 = log2(1 + k2*t1); contribution c1*t2 (ln2 folded into c1,k2)
        float t1 = __builtin_amdgcn_logf(1.0f + pw);
        float t2 = __builtin_amdgcn_logf(fmaf(p0.z, t1, 1.0f));
        // poly: c5*x + c6*x^2 + c7*x^3 + c8*x^4 (Horner)
        float q = fmaf(p1.w, xr, p1.z);
        q = fmaf(q, xr, p1.y);
        q = fmaf(q, xr, p1.x);
        acc = fmaf(q, xr, acc);
        acc = fmaf(p0.w, t2, acc);
    }
}

__global__ __launch_bounds__(256) void log_act_kernel(
    const float* __restrict__ x, float* __restrict__ out)
{
    // Transposed tile: xs_t[i][row]. Per-i fragment for a thread's 4 rows is
    // 16B contiguous -> ONE broadcast ds_read_b128 (same addr across lanes,
    // conflict-free) instead of 4 ds_read_b32.
    __shared__ float xs_t[IN_DIM][BTILE];
    const int tid = threadIdx.x;
    const int b0  = blockIdx.x * BTILE;

    // Staging with transpose + ReLU. thread -> (row = tid&15, ig = tid>>4):
    // global read: 16B per lane, each 64B line fully covered by 4 lanes.
    // LDS write: 4x ds_write_b32, 4-way bank aliasing (1.58x, once per block).
    {
        const int row = tid & 15;
        const int ig  = tid >> 4;          // i-group 0..15
        float4 v = *(const float4*)(x + (b0 + row) * IN_DIM + ig * 4);
        xs_t[ig * 4 + 0][row] = fmaxf(v.x, 0.0f);
        xs_t[ig * 4 + 1][row] = fmaxf(v.y, 0.0f);
        xs_t[ig * 4 + 2][row] = fmaxf(v.z, 0.0f);
        xs_t[ig * 4 + 3][row] = fmaxf(v.w, 0.0f);
    }
    __syncthreads();

    const int o  = tid & 63;
    const int bg = tid >> 6;   // 0..3

    float acc[RPT];
    #pragma unroll
    for (int r = 0; r < RPT; ++r) acc[r] = 0.0f;

    const float* tbase = g_table + o * 8;

    for (int i = 0; i < IN_DIM; ++i) {
        const float4* p = (const float4*)(tbase + i * OUT_DIM * 8);
        float4 p0 = p[0];   // k3, b4, k2, c1
        float4 p1 = p[1];   // c5, c6, c7, c8
        float4 xv = *(const float4*)&xs_t[i][bg * RPT];  // broadcast b128

        row_contrib(xv.x, p0, p1, acc[0]);
        row_contrib(xv.y, p0, p1, acc[1]);
        row_contrib(xv.z, p0, p1, acc[2]);
        row_contrib(xv.w, p0, p1, acc[3]);
    }

    #pragma unroll
    for (int r = 0; r < RPT; ++r) {
        int b = b0 + bg * RPT + r;
        out[b * OUT_DIM + o] = acc[r];
    }
}

extern "C" void kernel_launch(void* const* d_in, const int* in_sizes, int n_in,
                              void* d_out, int out_size, void* d_ws, size_t ws_size,
                              hipStream_t stream) {
    const float* x         = (const float*)d_in[0];
    const float* raw_gamma = (const float*)d_in[1];
    const float* w         = (const float*)d_in[2];
    const float* breaks    = (const float*)d_in[3];
    const float* coefs     = (const float*)d_in[4];
    const float* mu_p      = (const float*)d_in[5];
    const float* sigma_p   = (const float*)d_in[6];
    float* out = (float*)d_out;

    precompute_params<<<(OUT_DIM * IN_DIM + 63) / 64, 64, 0, stream>>>(
        raw_gamma, w, breaks, coefs, mu_p, sigma_p);

    log_act_kernel<<<B_TOTAL / BTILE, 256, 0, stream>>>(x, out);
}